// Round 2
// baseline (328.257 us; speedup 1.0000x reference)
//
#include <hip/hip_runtime.h>
#include <math.h>

#define NJ 25          // joints (voxel channels)
#define NJP 32         // padded channel stride in transposed layout (128B, float4-aligned)
#define VD 32
#define VH 128
#define VW 128
#define MAXNI 14
#define TEMP 20.0f
#define NEGINF (-10000.0f)
#define DHW (VD*VH*VW)        // 524288

// ---------------- Kernel A: invert the 14 init-bone affine transforms ----------------
__global__ void invert_tfs_kernel(const float* __restrict__ tfs,
                                  const int* __restrict__ bones,
                                  float* __restrict__ tinv, int ni) {
    int t = threadIdx.x;
    if (t >= ni) return;
    const float* T = tfs + (size_t)bones[t] * 16;
    // rows 0..2 = [R | t], row 3 = [0,0,0,1] (exact in the reference)
    double r00=T[0], r01=T[1], r02=T[2],  tx=T[3];
    double r10=T[4], r11=T[5], r12=T[6],  ty=T[7];
    double r20=T[8], r21=T[9], r22=T[10], tz=T[11];
    double c00 = r11*r22 - r12*r21;
    double c01 = r12*r20 - r10*r22;
    double c02 = r10*r21 - r11*r20;
    double det = r00*c00 + r01*c01 + r02*c02;
    double id  = 1.0/det;
    double i00 = c00*id;
    double i01 = (r02*r21 - r01*r22)*id;
    double i02 = (r01*r12 - r02*r11)*id;
    double i10 = c01*id;
    double i11 = (r00*r22 - r02*r20)*id;
    double i12 = (r02*r10 - r00*r12)*id;
    double i20 = c02*id;
    double i21 = (r01*r20 - r00*r21)*id;
    double i22 = (r00*r11 - r01*r10)*id;
    double itx = -(i00*tx + i01*ty + i02*tz);
    double ity = -(i10*tx + i11*ty + i12*tz);
    double itz = -(i20*tx + i21*ty + i22*tz);
    float* o = tinv + t*12;
    o[0]=(float)i00; o[1]=(float)i01; o[2] =(float)i02; o[3] =(float)itx;
    o[4]=(float)i10; o[5]=(float)i11; o[6] =(float)i12; o[7] =(float)ity;
    o[8]=(float)i20; o[9]=(float)i21; o[10]=(float)i22; o[11]=(float)itz;
}

// ---------------- Kernel B: transpose [J][D][H][W] -> [D][H][W][NJP] (pad 25->32) ----
// One block per (z,y) row. LDS stride 129 => conflict-free on both sides.
__global__ __launch_bounds__(256) void transpose_vox_kernel(const float* __restrict__ vox,
                                                            float* __restrict__ vt) {
    __shared__ float lds[NJ*129];
    int row = blockIdx.x;                  // z*VH + y  (0..4095)
    int t = threadIdx.x;
    for (int idx = t; idx < NJ*VW; idx += 256) {
        int j  = idx >> 7;                 // /128
        int xx = idx & 127;
        lds[j*129 + xx] = vox[(size_t)j*DHW + (size_t)row*VW + xx];
    }
    __syncthreads();
    float* out = vt + (size_t)row * (VW*NJP);
    for (int idx = t; idx < VW*NJP; idx += 256) {
        int xx = idx >> 5;                 // /32
        int j  = idx & 31;
        out[idx] = (j < NJ) ? lds[j*129 + xx] : 0.0f;
    }
}

// ---------------- Kernel C: main per-point deformer ----------------
__device__ __forceinline__ float f4g(const float4 v, int k) {
    return k==0 ? v.x : k==1 ? v.y : k==2 ? v.z : v.w;
}

// per-channel softmax-numerator + folded-warp accumulation.
// M read straight from global tfs: uniform address (j compile-time) -> s_load path.
#define CH_BODY(jj, vv) do {                                              \
    float ev = __expf(TEMP * (vv));                                       \
    s_sum += ev;                                                          \
    const float* M_ = &tfs[(jj)*16];                                      \
    E0 += ev*M_[0]; E1  += ev*M_[1];  E2  += ev*M_[2];  E3  += ev*M_[3];  \
    E4 += ev*M_[4]; E5  += ev*M_[5];  E6  += ev*M_[6];  E7  += ev*M_[7];  \
    E8 += ev*M_[8]; E9  += ev*M_[9];  E10 += ev*M_[10]; E11 += ev*M_[11]; \
    if ((jj) < 15) eArr[(jj)] = ev;                                       \
} while (0)

// 4 threads per point; thread `sub` handles inits i = sub, sub+4, ...
// VT=true: gather from padded transposed layout with float4 loads.
// VT=false: fallback, gather from original [J][D][H][W] (ws too small).
template<bool VT>
__global__ __launch_bounds__(256) void deformer_kernel(
        const float* __restrict__ x,
        const float* __restrict__ tfs,
        const float* __restrict__ vsrc,
        const float* __restrict__ tinv,
        float* __restrict__ out, int N, int ni) {
    int t   = threadIdx.x;
    int n   = blockIdx.x*64 + (t >> 2);
    int sub = t & 3;
    if (n >= N) return;

    float px = x[n*3+0], py = x[n*3+1], pz = x[n*3+2];

    float bestD = -3.0e38f;
    int   bestIdx = 0x7fffffff;
    float bF[15];
    float bcx = 0.f, bcy = 0.f, bcz = 0.f;
    #pragma unroll
    for (int k = 0; k < 15; ++k) bF[k] = 0.f;

    #pragma unroll 1
    for (int i = sub; i < ni; i += 4) {
        const float* Ti = &tinv[i*12];     // per-lane address; tiny table, L1-hot
        float cx = Ti[0]*px + Ti[1]*py + Ti[2] *pz + Ti[3];
        float cy = Ti[4]*px + Ti[5]*py + Ti[6] *pz + Ti[7];
        float cz = Ti[8]*px + Ti[9]*py + Ti[10]*pz + Ti[11];

        float gx = fminf(fmaxf((cx + 1.0f) * (0.5f*(VW-1)), 0.0f), (float)(VW-1));
        float gy = fminf(fmaxf((cy + 1.0f) * (0.5f*(VH-1)), 0.0f), (float)(VH-1));
        float gz = fminf(fmaxf((cz + 1.0f) * (0.5f*(VD-1)), 0.0f), (float)(VD-1));
        int x0 = (int)gx, y0 = (int)gy, z0 = (int)gz;   // gx>=0 => trunc == floor
        int x1 = min(x0+1, VW-1), y1 = min(y0+1, VH-1), z1 = min(z0+1, VD-1);
        float fx = gx - (float)x0, fy = gy - (float)y0, fz = gz - (float)z0;
        float ax = 1.0f - fx, ay = 1.0f - fy, az = 1.0f - fz;
        float w000 = ax*ay*az, w001 = fx*ay*az, w010 = ax*fy*az, w011 = fx*fy*az;
        float w100 = ax*ay*fz, w101 = fx*ay*fz, w110 = ax*fy*fz, w111 = fx*fy*fz;

        float s_sum = 0.0f;
        float E0=0,E1=0,E2=0,E3=0,E4=0,E5=0,E6=0,E7=0,E8=0,E9=0,E10=0,E11=0;
        float eArr[15];

        if (VT) {
            // padded transposed layout: voxel stride NJP floats (128B aligned)
            int o000 = ((z0*VH + y0)*VW + x0) * NJP;            // < 2^25, fits int
            int dz = (z1 - z0) * (VH*VW*NJP);
            int dy = (y1 - y0) * (VW*NJP);
            int dx = (x1 - x0) * NJP;
            int o001 = o000 + dx,      o010 = o000 + dy,      o011 = o000 + dy + dx;
            int o100 = o000 + dz,      o101 = o000 + dz + dx;
            int o110 = o000 + dz + dy, o111 = o000 + dz + dy + dx;

            #pragma unroll
            for (int j4 = 0; j4 < 7; ++j4) {
                const int jb = j4*4;
                float4 a000 = *(const float4*)&vsrc[o000 + jb];
                float4 a001 = *(const float4*)&vsrc[o001 + jb];
                float4 a010 = *(const float4*)&vsrc[o010 + jb];
                float4 a011 = *(const float4*)&vsrc[o011 + jb];
                float4 a100 = *(const float4*)&vsrc[o100 + jb];
                float4 a101 = *(const float4*)&vsrc[o101 + jb];
                float4 a110 = *(const float4*)&vsrc[o110 + jb];
                float4 a111 = *(const float4*)&vsrc[o111 + jb];
                #pragma unroll
                for (int k = 0; k < 4; ++k) {
                    const int j = jb + k;
                    if (j < NJ) {
                        float v = f4g(a000,k)*w000 + f4g(a001,k)*w001
                                + f4g(a010,k)*w010 + f4g(a011,k)*w011
                                + f4g(a100,k)*w100 + f4g(a101,k)*w101
                                + f4g(a110,k)*w110 + f4g(a111,k)*w111;
                        CH_BODY(j, v);
                    }
                }
            }
        } else {
            int b000 = (z0*VH + y0)*VW + x0;
            int dz = (z1 - z0) * (VH*VW);
            int dy = (y1 - y0) * VW;
            int dx = (x1 - x0);
            #pragma unroll
            for (int j = 0; j < NJ; ++j) {
                const float* vj = vsrc + (size_t)j*DHW + b000;
                float v = vj[0]*w000        + vj[dx]*w001
                        + vj[dy]*w010       + vj[dy+dx]*w011
                        + vj[dz]*w100       + vj[dz+dx]*w101
                        + vj[dz+dy]*w110    + vj[dz+dy+dx]*w111;
                CH_BODY(j, v);
            }
        }

        float invs = 1.0f / s_sum;
        float wxp = (E0*cx + E1*cy + E2 *cz + E3 ) * invs;
        float wyp = (E4*cx + E5*cy + E6 *cz + E7 ) * invs;
        float wzp = (E8*cx + E9*cy + E10*cz + E11) * invs;
        float dxp = wxp - px, dyp = wyp - py, dzp = wzp - pz;
        float err = sqrtf(dxp*dxp + dyp*dyp + dzp*dzp);
        float d = (err < 0.1f) ? -err : NEGINF;

        if (d > bestD || (d == bestD && i < bestIdx)) {
            bestD = d; bestIdx = i;
            #pragma unroll
            for (int k = 0; k < 15; ++k) bF[k] = eArr[k]*invs;
            bcx = cx; bcy = cy; bcz = cz;
        }
    }

    // combine the 4 candidates (lanes 4k..4k+3) — argmax with first-index tie-break
    float od = __shfl_xor(bestD, 1); int oi = __shfl_xor(bestIdx, 1);
    if (od > bestD || (od == bestD && oi < bestIdx)) { bestD = od; bestIdx = oi; }
    od = __shfl_xor(bestD, 2); oi = __shfl_xor(bestIdx, 2);
    if (od > bestD || (od == bestD && oi < bestIdx)) { bestD = od; bestIdx = oi; }

    // exactly one of the 4 lanes owns the winning candidate's payload
    if (sub == (bestIdx & 3)) {
        float* o_d = out;                       // [N]
        float* o_f = out + N;                   // [N,15]
        float* o_m = out + (size_t)N*16;        // [N]
        float* o_w = out + (size_t)N*17;        // [N,3]
        o_d[n] = bestD;
        #pragma unroll
        for (int k = 0; k < 15; ++k) o_f[(size_t)n*15 + k] = bF[k];
        o_m[n] = (bestD > -9999.0f) ? 1.0f : 0.0f;   // mask[idx] <=> winner not NEG_INF
        o_w[(size_t)n*3+0] = bcx; o_w[(size_t)n*3+1] = bcy; o_w[(size_t)n*3+2] = bcz;
    }
}

extern "C" void kernel_launch(void* const* d_in, const int* in_sizes, int n_in,
                              void* d_out, int out_size, void* d_ws, size_t ws_size,
                              hipStream_t stream) {
    const float* x     = (const float*)d_in[0];   // [1,N,3]
    const float* tfs   = (const float*)d_in[1];   // [1,25,4,4]
    const float* vox   = (const float*)d_in[2];   // [1,25,32,128,128]
    const int*   bones = (const int*)  d_in[3];   // [14]
    int N  = in_sizes[0] / 3;
    int ni = in_sizes[3];

    float* ws = (float*)d_ws;
    size_t vt_floats = (size_t)DHW * NJP;                 // 16.78M floats = 67.1MB
    bool useVT = ws_size >= (vt_floats + 256) * sizeof(float);

    if (useVT) {
        float* vt   = ws;
        float* tinv = ws + vt_floats;
        hipLaunchKernelGGL(invert_tfs_kernel, dim3(1), dim3(64), 0, stream,
                           tfs, bones, tinv, ni);
        hipLaunchKernelGGL(transpose_vox_kernel, dim3(VD*VH), dim3(256), 0, stream,
                           vox, vt);
        hipLaunchKernelGGL((deformer_kernel<true>), dim3((N + 63)/64), dim3(256), 0, stream,
                           x, tfs, vt, tinv, (float*)d_out, N, ni);
    } else {
        float* tinv = ws;                                  // needs only 672B
        hipLaunchKernelGGL(invert_tfs_kernel, dim3(1), dim3(64), 0, stream,
                           tfs, bones, tinv, ni);
        hipLaunchKernelGGL((deformer_kernel<false>), dim3((N + 63)/64), dim3(256), 0, stream,
                           x, tfs, vox, tinv, (float*)d_out, N, ni);
    }
}